// Round 4
// baseline (161.429 us; speedup 1.0000x reference)
//
#include <hip/hip_runtime.h>

// LSTM autoencoder via bf16 MFMA, v12: v11 math + batch-half wave specialization.
// v10/v11 post-mortem: VALU busy ~39us (trans issue, confirmed by merged-rcp cut);
// region time 2x VALU issue -> exposed LDS burst at region start (all waves read
// h-operands after barrier; v10 doubled LDS reads and TLP gain vanished).
// v12: each wave owns ONE batch-half x 4 tiles (was 2 tiles x both halves):
//   z1/z4 waves: 2 h-reads/region (was 4); z2: 3 (was 6); z3: 1 (was 2).
// Phase-A LDS reads/region 72 -> 36; same cellUps (4/wave), same MFMA totals,
// same trans issue. proj: 2 waves x 1 half (was 1 wave x both).
// Geometry: 768 thr, 12 waves, grid 256, 1 block/CU.
// Waves 0..7: z1/z4, j = w>>1 (tile group, tiles j+4*tt), half = w&1.
// Waves 8..11: z2/z3, j2 = (w>>1)-4 (tiles j2+2*tt), half = w&1.
// log2e folded into weights/biases (gate-g rows x 2log2e); gates exp2(-acc).
// cellUp merged-rcp: 5 exp2 + 2 rcp. pkbf packs tile-pair h conversion.
// barLDS (lgkmcnt-only) in steady state; __syncthreads at phase transitions.
// aB (stride 264 u16, 32 rows): phA h1 dbuf p*64, h2 dbuf 128+p*32, latent 160..191;
//                               phB h4 dbuf p*64, latent 160 (preserved), h3 192+p*32.
// LDS: xAll 32x968 (60.5KB) + aB 32x264 (16.5KB) = ~77KB -> 1 block/CU.

#define TT 30
#define FF 16
#define NT 768

typedef unsigned short u16t;
typedef __attribute__((ext_vector_type(8))) short short8;
typedef __attribute__((ext_vector_type(4))) short short4v;
typedef __attribute__((ext_vector_type(4))) float floatx4;

#define MFMA(a, b, c) __builtin_amdgcn_mfma_f32_16x16x32_bf16(a, b, c, 0, 0, 0)

#if __has_builtin(__builtin_amdgcn_exp2f)
#define EXP2(x) __builtin_amdgcn_exp2f(x)
#else
#define EXP2(x) exp2f(x)
#endif

template <int P> struct IC { static constexpr int v = P; };

__device__ __forceinline__ float rcpf(float v) { return __builtin_amdgcn_rcpf(v); }
__device__ __forceinline__ u16t f2bf(float f) {
  unsigned int u = __float_as_uint(f);
  u = (u + 0x7FFFu + ((u >> 16) & 1u)) >> 16;
  return (u16t)u;
}
// packed f32x2 -> bf16x2 (RNE), one VALU op
__device__ __forceinline__ unsigned int pkbf(float a, float b) {
  unsigned int r;
  asm("v_cvt_pk_bf16_f32 %0, %1, %2" : "=v"(r) : "v"(a), "v"(b));
  return r;
}
// LDS-only barrier: wait ds ops, skip vmcnt drain.
__device__ __forceinline__ void barLDS() {
  asm volatile("s_waitcnt lgkmcnt(0)" ::: "memory");
  __builtin_amdgcn_s_barrier();
}
__device__ __forceinline__ short8 ldFragS(const float* p, float s) {
  const float4 lo = *(const float4*)p;
  const float4 hi = *(const float4*)(p + 4);
  short8 r;
  r[0] = (short)f2bf(lo.x * s); r[1] = (short)f2bf(lo.y * s);
  r[2] = (short)f2bf(lo.z * s); r[3] = (short)f2bf(lo.w * s);
  r[4] = (short)f2bf(hi.x * s); r[5] = (short)f2bf(hi.y * s);
  r[6] = (short)f2bf(hi.z * s); r[7] = (short)f2bf(hi.w * s);
  return r;
}
// acc pre-scaled: [i,f,o] x log2e, [g] x 2log2e. lane owns i,f,g,o of one unit.
// Merged-rcp: c = [c(1+ei)(1+eg) + (1-eg)(1+ef)] / [(1+ef)(1+ei)(1+eg)]
__device__ __forceinline__ float cellUp(const floatx4 acc, float& c) {
  float ei = EXP2(-acc[0]);
  float ef = EXP2(-acc[1]);
  float eg = EXP2(-acc[2]);
  float eo = EXP2(-acc[3]);
  float pig = (1.f + ei) * (1.f + eg);
  float pf  = 1.f + ef;
  float num = c * pig + (1.f - eg) * pf;
  c = num * rcpf(pf * pig);
  float ec = EXP2(-2.885390082f * c);
  return (1.f - ec) * rcpf((1.f + eo) * (1.f + ec));       // sig(o)*tanh(c)
}

__global__ __launch_bounds__(NT, 3) void lstm_ae_mfma12(
    const float* __restrict__ x,
    const float* __restrict__ Wih1, const float* __restrict__ Whh1, const float* __restrict__ b1,
    const float* __restrict__ Wih2, const float* __restrict__ Whh2, const float* __restrict__ b2,
    const float* __restrict__ Wih3, const float* __restrict__ Whh3, const float* __restrict__ b3,
    const float* __restrict__ Wih4, const float* __restrict__ Whh4, const float* __restrict__ b4,
    const float* __restrict__ Wout, const float* __restrict__ bout,
    float* __restrict__ out)
{
  __shared__ __align__(16) u16t xAll[32 * 968];  // x bf16, k16..31 zero-pad, stride 968
  __shared__ __align__(16) u16t aB[32 * 264];    // recurrent state, stride 264

  const int t = threadIdx.x;
  const int w = t >> 6, lane = t & 63;           // 12 waves
  const int q = lane >> 4, n = lane & 15;
  const int q8 = q * 8;
  const int bBase = blockIdx.x * 32;
  const int nlo = n >> 2, ngt = n & 3;
  const bool isZ1 = (w < 8);
  const int hf = w & 1;                          // batch half (rows n or n+16)
  const int jA = w >> 1;                         // z1/z4 tile group 0..3 (w<8)
  const int j2 = (w >> 1) - 4;                   // z2/z3 tile group 0..1 (w>=8)
  const int rh = (n + 16 * hf) * 264;            // this wave's aB row
  const int xh = (n + 16 * hf) * 968;            // this wave's x row

  const float L1 = 1.442695041f, L2 = 2.885390082f;
  const float sA = (ngt == 2) ? L2 : L1;         // gate-g rows scaled 2log2e

  // ================= init =================
  for (int i = t; i < 32 * 264; i += NT) aB[i] = 0;
  {
    const float* xb = x + (size_t)bBase * (TT * FF);
    for (int i4 = t; i4 < 3840; i4 += NT) {
      int e = i4 * 4;
      int b = e / 480, r = e - b * 480;
      int stp = r >> 4, f = r & 15;
      float4 v = *(const float4*)&xb[e];
      short4v s4 = { (short)f2bf(v.x), (short)f2bf(v.y), (short)f2bf(v.z), (short)f2bf(v.w) };
      *(short4v*)&xAll[b * 968 + stp * 32 + f] = s4;
    }
    for (int i = t; i < 15360; i += NT) {   // zero pads k=16..31
      int b = i / 480, r = i - b * 480;
      int stp = r >> 4, f = r & 15;
      xAll[b * 968 + stp * 32 + 16 + f] = 0;
    }
  }
  const short8 z8 = { 0, 0, 0, 0, 0, 0, 0, 0 };
  short8 wAf[4][3]; floatx4 biasA[4];            // z1 (waves 0..7) or z2 (waves 8..11)
  if (isZ1) {
#pragma unroll
    for (int tt = 0; tt < 4; ++tt) {
      int T = jA + 4 * tt;
      int row = ngt * 64 + T * 4 + nlo;
      wAf[tt][0] = z8;
      if (q < 2) wAf[tt][0] = ldFragS(&Wih1[row * 16 + q8], sA);
      wAf[tt][1] = ldFragS(&Whh1[row * 64 + q8], sA);
      wAf[tt][2] = ldFragS(&Whh1[row * 64 + 32 + q8], sA);
#pragma unroll
      for (int r = 0; r < 4; ++r) biasA[tt][r] = b1[r * 64 + T * 4 + q] * (r == 2 ? L2 : L1);
    }
  } else {
#pragma unroll
    for (int tt = 0; tt < 4; ++tt) {
      int T = j2 + 2 * tt;
      int row = ngt * 32 + T * 4 + nlo;
      wAf[tt][0] = ldFragS(&Wih2[row * 64 + q8], sA);
      wAf[tt][1] = ldFragS(&Wih2[row * 64 + 32 + q8], sA);
      wAf[tt][2] = ldFragS(&Whh2[row * 32 + q8], sA);
#pragma unroll
      for (int r = 0; r < 4; ++r) biasA[tt][r] = b2[r * 32 + T * 4 + q] * (r == 2 ? L2 : L1);
    }
  }
  __syncthreads();

  float cA[4] = {0.f, 0.f, 0.f, 0.f};
  short8 bxN;
  float hv[4];

  // ---- peel: z1(0) (h1(-1)=0) ----
  if (isZ1) {
    const short8 bx0 = *(const short8*)&xAll[xh + q8];
#pragma unroll
    for (int tt = 0; tt < 4; ++tt) {
      floatx4 a = biasA[tt];
      a = MFMA(wAf[tt][0], bx0, a);
      hv[tt] = cellUp(a, cA[tt]);
    }
    unsigned int pk01 = pkbf(hv[0], hv[1]);
    unsigned int pk23 = pkbf(hv[2], hv[3]);
    aB[rh + (jA + 0) * 4 + q] = (u16t)pk01;
    aB[rh + (jA + 4) * 4 + q] = (u16t)(pk01 >> 16);
    aB[rh + (jA + 8) * 4 + q] = (u16t)pk23;
    aB[rh + (jA + 12) * 4 + q] = (u16t)(pk23 >> 16);
    bxN = *(const short8*)&xAll[xh + 32 + q8];   // prefetch x(1)
  }
  barLDS();

  // ================= Phase A: 29 skewed regions, 1 barrier each =================
  auto stepA = [&](int st, auto pc) {
    constexpr int p = decltype(pc)::v;
    const short8 h1a = *(const short8*)&aB[rh + p * 64 + q8];        // this half only
    const short8 h1b = *(const short8*)&aB[rh + p * 64 + 32 + q8];
    if (isZ1) {  // z1(st+1): 4 tiles, one half
#pragma unroll
      for (int tt = 0; tt < 4; ++tt) {
        floatx4 a = biasA[tt];
        a = MFMA(wAf[tt][0], bxN, a);
        a = MFMA(wAf[tt][1], h1a, a);
        a = MFMA(wAf[tt][2], h1b, a);
        hv[tt] = cellUp(a, cA[tt]);
      }
      unsigned int pk01 = pkbf(hv[0], hv[1]);
      unsigned int pk23 = pkbf(hv[2], hv[3]);
      aB[rh + (1 - p) * 64 + (jA + 0) * 4 + q] = (u16t)pk01;
      aB[rh + (1 - p) * 64 + (jA + 4) * 4 + q] = (u16t)(pk01 >> 16);
      aB[rh + (1 - p) * 64 + (jA + 8) * 4 + q] = (u16t)pk23;
      aB[rh + (1 - p) * 64 + (jA + 12) * 4 + q] = (u16t)(pk23 >> 16);
      const int nx = (st + 2 < TT) ? st + 2 : TT - 1;
      bxN = *(const short8*)&xAll[xh + nx * 32 + q8];
    } else {     // z2(st): 4 tiles, one half
      const short8 h2 = *(const short8*)&aB[rh + 128 + (1 - p) * 32 + q8];
#pragma unroll
      for (int tt = 0; tt < 4; ++tt) {
        floatx4 a = biasA[tt];
        a = MFMA(wAf[tt][0], h1a, a);
        a = MFMA(wAf[tt][1], h1b, a);
        a = MFMA(wAf[tt][2], h2, a);
        hv[tt] = cellUp(a, cA[tt]);
      }
      unsigned int pk01 = pkbf(hv[0], hv[1]);
      unsigned int pk23 = pkbf(hv[2], hv[3]);
      aB[rh + 128 + p * 32 + (j2 + 0) * 4 + q] = (u16t)pk01;
      aB[rh + 128 + p * 32 + (j2 + 2) * 4 + q] = (u16t)(pk01 >> 16);
      aB[rh + 128 + p * 32 + (j2 + 4) * 4 + q] = (u16t)pk23;
      aB[rh + 128 + p * 32 + (j2 + 6) * 4 + q] = (u16t)(pk23 >> 16);
    }
    barLDS();
  };
  for (int st = 0; st < 28; st += 2) { stepA(st, IC<0>{}); stepA(st + 1, IC<1>{}); }
  stepA(28, IC<0>{});
  // ---- tail: z2(29); h1(29)@64, h2(28)@128 -> latent 160..191 ----
  if (!isZ1) {
    const short8 h1a = *(const short8*)&aB[rh + 64 + q8];
    const short8 h1b = *(const short8*)&aB[rh + 96 + q8];
    const short8 h2  = *(const short8*)&aB[rh + 128 + q8];
#pragma unroll
    for (int tt = 0; tt < 4; ++tt) {
      floatx4 a = biasA[tt];
      a = MFMA(wAf[tt][0], h1a, a);
      a = MFMA(wAf[tt][1], h1b, a);
      a = MFMA(wAf[tt][2], h2, a);
      hv[tt] = cellUp(a, cA[tt]);
    }
    unsigned int pk01 = pkbf(hv[0], hv[1]);
    unsigned int pk23 = pkbf(hv[2], hv[3]);
    aB[rh + 160 + (j2 + 0) * 4 + q] = (u16t)pk01;
    aB[rh + 160 + (j2 + 2) * 4 + q] = (u16t)(pk01 >> 16);
    aB[rh + 160 + (j2 + 4) * 4 + q] = (u16t)pk23;
    aB[rh + 160 + (j2 + 6) * 4 + q] = (u16t)(pk23 >> 16);
  }
  __syncthreads();

  // ================= transition: phase-B weights; zero h4(-1) =================
  short8 wBf[4][3]; floatx4 biasB[4];
  short8 wof[2]; floatx4 biasO;
  short8 w3h[4]; floatx4 acc3c[4];               // z3: hoisted b3 + Wih3*latent per tile
  if (isZ1) {
#pragma unroll
    for (int tt = 0; tt < 4; ++tt) {
      int T = jA + 4 * tt;
      int row = ngt * 64 + T * 4 + nlo;
      wBf[tt][0] = ldFragS(&Wih4[row * 32 + q8], sA);
      wBf[tt][1] = ldFragS(&Whh4[row * 64 + q8], sA);
      wBf[tt][2] = ldFragS(&Whh4[row * 64 + 32 + q8], sA);
#pragma unroll
      for (int r = 0; r < 4; ++r) biasB[tt][r] = b4[r * 64 + T * 4 + q] * (r == 2 ? L2 : L1);
    }
    wof[0] = ldFragS(&Wout[n * 64 + q8], 1.f);
    wof[1] = ldFragS(&Wout[n * 64 + 32 + q8], 1.f);
    biasO = *(const floatx4*)&bout[q * 4];
  } else {
    const short8 blat = *(const short8*)&aB[rh + 160 + q8];
#pragma unroll
    for (int tt = 0; tt < 4; ++tt) {
      int T = j2 + 2 * tt;
      int row = ngt * 32 + T * 4 + nlo;
      const short8 w3i = ldFragS(&Wih3[row * 32 + q8], sA);
      w3h[tt] = ldFragS(&Whh3[row * 32 + q8], sA);
      floatx4 b3v;
#pragma unroll
      for (int r = 0; r < 4; ++r) b3v[r] = b3[r * 32 + T * 4 + q] * (r == 2 ? L2 : L1);
      acc3c[tt] = MFMA(w3i, blat, b3v);
    }
  }
  for (int i = t; i < 2048; i += NT) aB[(i >> 6) * 264 + 64 + (i & 63)] = 0;  // h4(-1)=0
  __syncthreads();

  float cB[4] = {0.f, 0.f, 0.f, 0.f};

  // ---- peel: z3(0) (h3(-1)=0 -> acc is the hoisted const) ----
  if (!isZ1) {
#pragma unroll
    for (int tt = 0; tt < 4; ++tt) hv[tt] = cellUp(acc3c[tt], cB[tt]);
    unsigned int pk01 = pkbf(hv[0], hv[1]);
    unsigned int pk23 = pkbf(hv[2], hv[3]);
    aB[rh + 192 + (j2 + 0) * 4 + q] = (u16t)pk01;
    aB[rh + 192 + (j2 + 2) * 4 + q] = (u16t)(pk01 >> 16);
    aB[rh + 192 + (j2 + 4) * 4 + q] = (u16t)pk23;
    aB[rh + 192 + (j2 + 6) * 4 + q] = (u16t)(pk23 >> 16);
  }
  barLDS();

  // ================= Phase B: 29 skewed regions, 1 barrier each =================
  auto stepB = [&](int st, auto pc) {
    constexpr int p = decltype(pc)::v;
    const short8 h3 = *(const short8*)&aB[rh + 192 + p * 32 + q8];   // this half only
    if (isZ1) {  // z4(st): 4 tiles, one half + rotating proj(st-1)
      const short8 h4a = *(const short8*)&aB[rh + (1 - p) * 64 + q8];
      const short8 h4b = *(const short8*)&aB[rh + (1 - p) * 64 + 32 + q8];
#pragma unroll
      for (int tt = 0; tt < 4; ++tt) {
        floatx4 a = biasB[tt];
        a = MFMA(wBf[tt][0], h3, a);
        a = MFMA(wBf[tt][1], h4a, a);
        a = MFMA(wBf[tt][2], h4b, a);
        hv[tt] = cellUp(a, cB[tt]);
      }
      unsigned int pk01 = pkbf(hv[0], hv[1]);
      unsigned int pk23 = pkbf(hv[2], hv[3]);
      aB[rh + p * 64 + (jA + 0) * 4 + q] = (u16t)pk01;
      aB[rh + p * 64 + (jA + 4) * 4 + q] = (u16t)(pk01 >> 16);
      aB[rh + p * 64 + (jA + 8) * 4 + q] = (u16t)pk23;
      aB[rh + p * 64 + (jA + 12) * 4 + q] = (u16t)(pk23 >> 16);
      if (st > 0 && jA == ((st - 1) & 3)) {      // 2 proj waves (one per half)
        floatx4 y = biasO;
        y = MFMA(wof[0], h4a, y);
        y = MFMA(wof[1], h4b, y);
        *(floatx4*)&out[((size_t)(bBase + n + 16 * hf) * TT + (st - 1)) * FF + q * 4] = y;
      }
    } else {     // z3(st+1): 4 tiles, one half (input term hoisted)
#pragma unroll
      for (int tt = 0; tt < 4; ++tt) {
        floatx4 a = MFMA(w3h[tt], h3, acc3c[tt]);
        hv[tt] = cellUp(a, cB[tt]);
      }
      unsigned int pk01 = pkbf(hv[0], hv[1]);
      unsigned int pk23 = pkbf(hv[2], hv[3]);
      aB[rh + 192 + (1 - p) * 32 + (j2 + 0) * 4 + q] = (u16t)pk01;
      aB[rh + 192 + (1 - p) * 32 + (j2 + 2) * 4 + q] = (u16t)(pk01 >> 16);
      aB[rh + 192 + (1 - p) * 32 + (j2 + 4) * 4 + q] = (u16t)pk23;
      aB[rh + 192 + (1 - p) * 32 + (j2 + 6) * 4 + q] = (u16t)(pk23 >> 16);
    }
    barLDS();
  };
  for (int st = 0; st < 28; st += 2) { stepB(st, IC<0>{}); stepB(st + 1, IC<1>{}); }
  stepB(28, IC<0>{});
  // ---- tail: z4(29) (h3(29)@224, h4(28)@0); proj(28); proj(29) ----
  if (isZ1) {
    const short8 h3  = *(const short8*)&aB[rh + 224 + q8];
    const short8 h4a = *(const short8*)&aB[rh + q8];
    const short8 h4b = *(const short8*)&aB[rh + 32 + q8];
#pragma unroll
    for (int tt = 0; tt < 4; ++tt) {
      floatx4 a = biasB[tt];
      a = MFMA(wBf[tt][0], h3, a);
      a = MFMA(wBf[tt][1], h4a, a);
      a = MFMA(wBf[tt][2], h4b, a);
      hv[tt] = cellUp(a, cB[tt]);
    }
    unsigned int pk01 = pkbf(hv[0], hv[1]);
    unsigned int pk23 = pkbf(hv[2], hv[3]);
    aB[rh + 64 + (jA + 0) * 4 + q] = (u16t)pk01;
    aB[rh + 64 + (jA + 4) * 4 + q] = (u16t)(pk01 >> 16);
    aB[rh + 64 + (jA + 8) * 4 + q] = (u16t)pk23;
    aB[rh + 64 + (jA + 12) * 4 + q] = (u16t)(pk23 >> 16);
    if (jA == 0) {  // proj(28), one wave per half
      floatx4 y = biasO;
      y = MFMA(wof[0], h4a, y);
      y = MFMA(wof[1], h4b, y);
      *(floatx4*)&out[((size_t)(bBase + n + 16 * hf) * TT + 28) * FF + q * 4] = y;
    }
  }
  barLDS();
  if (isZ1 && jA == 1) {  // proj(29): h4(29)@64/96, one wave per half
    const short8 ba = *(const short8*)&aB[rh + 64 + q8];
    const short8 bb = *(const short8*)&aB[rh + 96 + q8];
    floatx4 y = biasO;
    y = MFMA(wof[0], ba, y);
    y = MFMA(wof[1], bb, y);
    *(floatx4*)&out[((size_t)(bBase + n + 16 * hf) * TT + 29) * FF + q * 4] = y;
  }
}

extern "C" void kernel_launch(void* const* d_in, const int* in_sizes, int n_in,
                              void* d_out, int out_size, void* d_ws, size_t ws_size,
                              hipStream_t stream) {
  const float* x    = (const float*)d_in[0];
  const float* Wih1 = (const float*)d_in[1];
  const float* Whh1 = (const float*)d_in[2];
  const float* b1   = (const float*)d_in[3];
  const float* Wih2 = (const float*)d_in[4];
  const float* Whh2 = (const float*)d_in[5];
  const float* b2   = (const float*)d_in[6];
  const float* Wih3 = (const float*)d_in[7];
  const float* Whh3 = (const float*)d_in[8];
  const float* b3   = (const float*)d_in[9];
  const float* Wih4 = (const float*)d_in[10];
  const float* Whh4 = (const float*)d_in[11];
  const float* b4   = (const float*)d_in[12];
  const float* Wout = (const float*)d_in[13];
  const float* bout = (const float*)d_in[14];
  float* out = (float*)d_out;

  const int B = in_sizes[0] / (TT * FF);   // 8192
  dim3 grid(B / 32), block(NT);
  lstm_ae_mfma12<<<grid, block, 0, stream>>>(
      x, Wih1, Whh1, b1, Wih2, Whh2, b2, Wih3, Whh3, b3,
      Wih4, Whh4, b4, Wout, bout, out);
}